// Round 3
// baseline (2820.649 us; speedup 1.0000x reference)
//
#include <hip/hip_runtime.h>
#include <hip/hip_bf16.h>
#include <stdint.h>

#define D_MODEL 2048
#define D_FFN   8192
#define NTOK    8192
#define TOPK    256

typedef __bf16 bf16x8 __attribute__((ext_vector_type(8)));
typedef __bf16 bf16x4 __attribute__((ext_vector_type(4)));
typedef float  f32x4  __attribute__((ext_vector_type(4)));

// ---------------------------------------------------------------------------
// global -> LDS direct (16B per lane; LDS dest = wave-uniform base + lane*16)
// ---------------------------------------------------------------------------
__device__ inline void load_lds16(const void* g, void* l) {
    __builtin_amdgcn_global_load_lds((__attribute__((address_space(1))) void*)g,
                                     (__attribute__((address_space(3))) void*)l,
                                     16, 0, 0);
}

// ---------------------------------------------------------------------------
// bf16 GEMM, C[M,N] fp32 = sum_seg A_seg[M,segK] * B_seg[N,segK]^T
// m97 structure: 128x128 tile, BK=64, 4 waves (2x2), 16x16x32 MFMA.
// ---------------------------------------------------------------------------
template<int NSEG>
__global__ __launch_bounds__(256)
void gemm_bt(const __bf16* __restrict__ A0, const __bf16* __restrict__ A1,
             const __bf16* __restrict__ A2,
             const __bf16* __restrict__ B0, const __bf16* __restrict__ B1,
             const __bf16* __restrict__ B2,
             float* __restrict__ C, int segK, int ldc)
{
    __shared__ __align__(16) __bf16 sA[128][64];   // 16 KB
    __shared__ __align__(16) __bf16 sB[128][64];   // 16 KB

    const int tid  = threadIdx.x;
    const int lane = tid & 63;
    const int wid  = tid >> 6;
    const int mb   = blockIdx.y;
    const int nb   = blockIdx.x;

    f32x4 acc[4][4] = {};

    const int stR = wid * 8 + (lane >> 3);
    const int stC = (lane & 7) * 8;
    const int NKT = (NSEG * segK) / 64;

    for (int kt = 0; kt < NKT; ++kt) {
        const int kg  = kt * 64;
        const int seg = kg / segK;
        const int kin = kg - seg * segK;
        const __bf16* Aseg = (NSEG == 1 || seg == 0) ? A0 : (seg == 1 ? A1 : A2);
        const __bf16* Bseg = (NSEG == 1 || seg == 0) ? B0 : (seg == 1 ? B1 : B2);

        #pragma unroll
        for (int i = 0; i < 4; ++i) {
            const __bf16* gA = Aseg + (size_t)(mb * 128 + i * 32 + stR) * segK + (kin + stC);
            const __bf16* gB = Bseg + (size_t)(nb * 128 + i * 32 + stR) * segK + (kin + stC);
            load_lds16(gA, &sA[i * 32 + wid * 8][0]);
            load_lds16(gB, &sB[i * 32 + wid * 8][0]);
        }
        __syncthreads();

        const int wm = (wid >> 1) * 64;
        const int wn = (wid & 1) * 64;
        const int fr = lane & 15;
        const int fk = (lane >> 4) * 8;
        #pragma unroll
        for (int kk = 0; kk < 2; ++kk) {
            bf16x8 af[4], bfr[4];
            #pragma unroll
            for (int mi = 0; mi < 4; ++mi)
                af[mi] = *(const bf16x8*)&sA[wm + mi * 16 + fr][kk * 32 + fk];
            #pragma unroll
            for (int ni = 0; ni < 4; ++ni)
                bfr[ni] = *(const bf16x8*)&sB[wn + ni * 16 + fr][kk * 32 + fk];
            #pragma unroll
            for (int mi = 0; mi < 4; ++mi)
                #pragma unroll
                for (int ni = 0; ni < 4; ++ni)
                    acc[mi][ni] = __builtin_amdgcn_mfma_f32_16x16x32_bf16(
                        af[mi], bfr[ni], acc[mi][ni], 0, 0, 0);
        }
        __syncthreads();
    }

    const int wm = (wid >> 1) * 64;
    const int wn = (wid & 1) * 64;
    const int orow = (lane >> 4) * 4;
    const int ocol = lane & 15;
    #pragma unroll
    for (int mi = 0; mi < 4; ++mi)
        #pragma unroll
        for (int ni = 0; ni < 4; ++ni)
            #pragma unroll
            for (int j = 0; j < 4; ++j) {
                const int r = mb * 128 + wm + mi * 16 + orow + j;
                const int c = nb * 128 + wn + ni * 16 + ocol;
                C[(size_t)r * ldc + c] = acc[mi][ni][j];
            }
}

// ---------------------------------------------------------------------------
__global__ __launch_bounds__(256)
void split_convert(const float* __restrict__ in, __bf16* __restrict__ hi,
                   __bf16* __restrict__ lo, int n4)
{
    const int i = blockIdx.x * 256 + threadIdx.x;
    if (i >= n4) return;
    const float4 v = ((const float4*)in)[i];
    float f[4] = {v.x, v.y, v.z, v.w};
    bf16x4 h, l;
    #pragma unroll
    for (int j = 0; j < 4; ++j) {
        __bf16 hb = (__bf16)f[j];
        h[j] = hb;
        l[j] = (__bf16)(f[j] - (float)hb);
    }
    ((bf16x4*)hi)[i] = h;
    ((bf16x4*)lo)[i] = l;
}

// ---------------------------------------------------------------------------
template<bool SPLIT>
__global__ __launch_bounds__(256)
void transpose_bf16(const float* __restrict__ in, __bf16* __restrict__ outHi,
                    __bf16* __restrict__ outLo, int R, int C)
{
    __shared__ float tile[32][33];
    const int bx = blockIdx.x * 32;
    const int by = blockIdx.y * 32;
    const int tx = threadIdx.x & 31;
    const int ty = threadIdx.x >> 5;
    #pragma unroll
    for (int i = 0; i < 4; ++i)
        tile[ty + 8 * i][tx] = in[(size_t)(by + ty + 8 * i) * C + (bx + tx)];
    __syncthreads();
    #pragma unroll
    for (int i = 0; i < 4; ++i) {
        const float v = tile[tx][ty + 8 * i];
        const size_t o = (size_t)(bx + ty + 8 * i) * R + (by + tx);
        const __bf16 h = (__bf16)v;
        outHi[o] = h;
        if (SPLIT) outLo[o] = (__bf16)(v - (float)h);
    }
}

// ---------------------------------------------------------------------------
// exact top-256 per row of G[rows][D_FFN] fp32 (G computed to ~1e-6):
// radix-select pivot, then fp64-exact arbitration of the ambiguous boundary
// (|g - vT| <= EPS) using the ORIGINAL fp32 x row and w_gate columns.
// Matches an fp64 reference's selection (value desc, index asc tie-break).
// ---------------------------------------------------------------------------
#define TK_EPS 3e-5f
#define TK_MAXA 64

__global__ __launch_bounds__(256)
void topk256(const float* __restrict__ G, const float* __restrict__ xblk,
             const float* __restrict__ wgate,
             int* __restrict__ idxOut, float* __restrict__ gkOut)
{
    const int row = blockIdx.x;
    const int t = threadIdx.x;
    const int lane = t & 63;
    const int wid  = t >> 6;

    __shared__ unsigned keys[D_FFN];    // 32 KB
    __shared__ float    xr[D_MODEL];    //  8 KB
    __shared__ unsigned hist[256];
    __shared__ unsigned scanb[256];
    __shared__ int      sIdx[TOPK];
    __shared__ float    sVal[TOPK];
    __shared__ int      ambIdx[TK_MAXA];
    __shared__ double   ambVal[TK_MAXA];
    __shared__ double   redW[4];
    __shared__ unsigned sh_bin, sh_above, sh_nc, sh_na, sh_fill;

    const float* g = G + (size_t)row * D_FFN;
    const float* xrow = xblk + (size_t)row * D_MODEL;
    for (int i = t; i < D_FFN; i += 256) {
        const unsigned u = __float_as_uint(g[i]);
        keys[i] = (u & 0x80000000u) ? ~u : (u | 0x80000000u);  // descending-monotone
    }
    for (int i = t; i < D_MODEL; i += 256) xr[i] = xrow[i];
    if (t == 0) { sh_nc = 0; sh_na = 0; sh_fill = 0; }
    __syncthreads();

    // ---- radix select the 256th-largest key ----
    unsigned prefix = 0, pmask = 0;
    int remaining = TOPK;
    for (int shift = 24; shift >= 0; shift -= 8) {
        hist[t] = 0;
        __syncthreads();
        for (int i = t; i < D_FFN; i += 256) {
            const unsigned k = keys[i];
            if ((k & pmask) == prefix) atomicAdd(&hist[(k >> shift) & 255u], 1u);
        }
        __syncthreads();
        scanb[t] = hist[t];
        __syncthreads();
        for (int off = 1; off < 256; off <<= 1) {   // inclusive suffix scan
            const unsigned add = (t + off < 256) ? scanb[t + off] : 0u;
            __syncthreads();
            scanb[t] += add;
            __syncthreads();
        }
        const unsigned above = (t == 255) ? 0u : scanb[t + 1];
        if (scanb[t] >= (unsigned)remaining && above < (unsigned)remaining) {
            sh_bin = (unsigned)t;
            sh_above = above;
        }
        __syncthreads();
        prefix |= sh_bin << shift;
        pmask  |= 0xFFu << shift;
        remaining -= (int)sh_above;
        __syncthreads();
    }
    const unsigned Tkey = prefix;
    const float vT = __uint_as_float((Tkey & 0x80000000u) ? (Tkey & 0x7FFFFFFFu) : ~Tkey);

    // ---- classify: certain (> vT+EPS) vs ambiguous (within +-EPS) ----
    for (int i = t; i < D_FFN; i += 256) {
        const unsigned k = keys[i];
        const float f = __uint_as_float((k & 0x80000000u) ? (k & 0x7FFFFFFFu) : ~k);
        if (f > vT + TK_EPS) {
            const unsigned p = atomicAdd(&sh_nc, 1u);
            sIdx[p] = i;
            sVal[p] = f;
        } else if (f >= vT - TK_EPS) {
            const unsigned p = atomicAdd(&sh_na, 1u);
            if (p < TK_MAXA) ambIdx[p] = i;
        }
    }
    __syncthreads();
    const int nc = (int)sh_nc;                       // < 256 by pivot definition
    const int na = min((int)sh_na, TK_MAXA);
    const int need = TOPK - nc;                      // 1 <= need <= na (generic data)

    if (need >= na) {
        // uncontested: all ambiguous candidates selected; computed G suffices
        if (t < na) {
            const unsigned k = keys[ambIdx[t]];
            sIdx[nc + t] = ambIdx[t];
            sVal[nc + t] = __uint_as_float((k & 0x80000000u) ? (k & 0x7FFFFFFFu) : ~k);
        }
        __syncthreads();
    } else {
        // contested boundary: fp64-exact dots for the na candidates
        for (int j = 0; j < na; ++j) {
            const int col = ambIdx[j];
            double p = 0.0;
            for (int k = t; k < D_MODEL; k += 256)
                p += (double)xr[k] * (double)wgate[(size_t)k * D_FFN + col];
            #pragma unroll
            for (int o = 32; o > 0; o >>= 1) p += __shfl_xor(p, o, 64);
            if (lane == 0) redW[wid] = p;
            __syncthreads();
            if (t == 0) ambVal[j] = (redW[0] + redW[1]) + (redW[2] + redW[3]);
            __syncthreads();
        }
        // rank by (exact value desc, index asc); select top-`need`
        if (t < na) {
            const double v = ambVal[t];
            const int    c = ambIdx[t];
            int r = 0;
            for (int j = 0; j < na; ++j) {
                const double vj = ambVal[j];
                if (vj > v || (vj == v && ambIdx[j] < c)) r++;
            }
            if (r < need) {
                const unsigned p = atomicAdd(&sh_fill, 1u);
                sIdx[nc + p] = c;
                sVal[nc + p] = (float)v;
            }
        }
        __syncthreads();
    }

    idxOut[(size_t)row * TOPK + t] = sIdx[t];
    gkOut[(size_t)row * TOPK + t] = sVal[t];
}

// ---------------------------------------------------------------------------
__global__ __launch_bounds__(256)
void z_fused(const int* __restrict__ idx, const float* __restrict__ gk,
             const float* __restrict__ U, __bf16* __restrict__ Zd)
{
    const int r = blockIdx.x, t = threadIdx.x;
    const int p = r * TOPK + t;
    const int c = idx[p];
    const float g = gk[p];
    const float u = U[(size_t)r * D_FFN + c];
    const float s = g / (1.0f + __expf(-g));
    Zd[(size_t)r * D_FFN + c] = (__bf16)(s * u);
}

__global__ __launch_bounds__(256)
void zero_buf(float4* __restrict__ p, int n)
{
    int i = blockIdx.x * 256 + threadIdx.x;
    const int stride = gridDim.x * 256;
    for (; i < n; i += stride) p[i] = make_float4(0.f, 0.f, 0.f, 0.f);
}

// ---------------------------------------------------------------------------
extern "C" void kernel_launch(void* const* d_in, const int* in_sizes, int n_in,
                              void* d_out, int out_size, void* d_ws, size_t ws_size,
                              hipStream_t stream)
{
    const float* x  = (const float*)d_in[0];
    const float* wg = (const float*)d_in[1];
    const float* wu = (const float*)d_in[2];
    const float* wd = (const float*)d_in[3];
    float* out = (float*)d_out;

    const size_t SZ_XB = (size_t)NTOK * D_MODEL * 2;
    const size_t SZ_WB = (size_t)D_FFN * D_MODEL * 2;
    const size_t SZ_IK = (size_t)NTOK * TOPK * 4;
    char* ws = (char*)d_ws;
    size_t off = 0;
    auto alloc = [&](size_t bytes) -> char* {
        char* p = ws + off;
        off += (bytes + 255) & ~(size_t)255;
        return p;
    };
    __bf16* x_hi  = (__bf16*)alloc(SZ_XB);
    __bf16* x_lo  = (__bf16*)alloc(SZ_XB);   // after G phase: reused as Zd block
    __bf16* wT_a  = (__bf16*)alloc(SZ_WB);   // wgT_hi, then wuT
    __bf16* wT_b  = (__bf16*)alloc(SZ_WB);   // wgT_lo, then wdT
    int*    idx   = (int*)  alloc(SZ_IK);
    float*  gk    = (float*)alloc(SZ_IK);
    const size_t fixed = off;

    int RB = 2048;
    while (RB > 128 && fixed + (size_t)RB * D_FFN * 4 > ws_size) RB >>= 1;
    float* Eblk = (float*)alloc((size_t)RB * D_FFN * 4);
    __bf16* Zdb = x_lo;
    const int NRB = NTOK / RB;

    // 1) operand conversions for the G phase
    split_convert<<<(NTOK * D_MODEL / 4 + 255) / 256, 256, 0, stream>>>(
        x, x_hi, x_lo, NTOK * D_MODEL / 4);
    transpose_bf16<true><<<dim3(D_FFN / 32, D_MODEL / 32), 256, 0, stream>>>(
        wg, wT_a, wT_b, D_MODEL, D_FFN);

    // 2) G phase per row-block: stacked-K bf16 GEMM -> exact topk (fp64 fixup)
    for (int rb = 0; rb < NRB; ++rb) {
        const size_t aoff = (size_t)rb * RB * D_MODEL;
        gemm_bt<3><<<dim3(D_FFN / 128, RB / 128), 256, 0, stream>>>(
            x_hi + aoff, x_lo + aoff, x_hi + aoff,
            wT_a, wT_a, wT_b, Eblk, D_MODEL, D_FFN);
        topk256<<<RB, 256, 0, stream>>>(
            Eblk, x + aoff, wg,
            idx + (size_t)rb * RB * TOPK, gk + (size_t)rb * RB * TOPK);
    }

    // 3) weight conversions for U/down phases
    transpose_bf16<false><<<dim3(D_FFN / 32, D_MODEL / 32), 256, 0, stream>>>(
        wu, wT_a, nullptr, D_MODEL, D_FFN);
    transpose_bf16<false><<<dim3(D_MODEL / 32, D_FFN / 32), 256, 0, stream>>>(
        wd, wT_b, nullptr, D_FFN, D_MODEL);

    // 4) U -> z scatter -> down projection, per row-block
    for (int rb = 0; rb < NRB; ++rb) {
        const size_t aoff = (size_t)rb * RB * D_MODEL;
        gemm_bt<1><<<dim3(D_FFN / 128, RB / 128), 256, 0, stream>>>(
            x_hi + aoff, nullptr, nullptr, wT_a, nullptr, nullptr,
            Eblk, D_MODEL, D_FFN);
        zero_buf<<<2048, 256, 0, stream>>>((float4*)Zdb, RB * (D_FFN * 2 / 16));
        z_fused<<<RB, 256, 0, stream>>>(
            idx + (size_t)rb * RB * TOPK, gk + (size_t)rb * RB * TOPK, Eblk, Zdb);
        gemm_bt<1><<<dim3(D_MODEL / 128, RB / 128), 256, 0, stream>>>(
            Zdb, nullptr, nullptr, wT_b, nullptr, nullptr,
            out + (size_t)rb * RB * D_MODEL, D_FFN, D_MODEL);
    }
}